// Round 8
// baseline (969.570 us; speedup 1.0000x reference)
//
#include <hip/hip_runtime.h>

// ---------------- problem constants ----------------
#define Bc   4
#define Tc   2048
#define Dc   1024
#define Hc   16
#define DKc  64
#define DVc  128
#define QKDc 1024
#define VDc  2048
#define NPRJ 5120        // q|k|v|gate fused projection width
#define Mc   (Bc * Tc)   // 8192 tokens
#define SW   64          // scan LDS window (time steps)

typedef __bf16 bf16;
typedef __bf16 bf16x4 __attribute__((ext_vector_type(4)));
typedef __bf16 bf16x8 __attribute__((ext_vector_type(8)));
typedef float  f32x4  __attribute__((ext_vector_type(4)));

__device__ __forceinline__ float bf2f(bf16 v) { return (float)v; }
__device__ __forceinline__ bf16  f2bf(float v) { return (bf16)v; }
__device__ __forceinline__ float sigmoidf_(float x) { return 1.0f / (1.0f + __expf(-x)); }

// DPP adds (VALU pipe). 0xB1=quad_perm xor1, 0x4E=quad_perm xor2,
// 0x141=ROW_HALF_MIRROR. reduce8 sums each aligned 8-lane group (HW-verified r5-r7).
template <int CTRL>
__device__ __forceinline__ float dpp_add(float x) {
    int xi = __float_as_int(x);
    int yi = __builtin_amdgcn_update_dpp(0, xi, CTRL, 0xF, 0xF, true);
    return x + __int_as_float(yi);
}
__device__ __forceinline__ float reduce8(float x) {
    x = dpp_add<0xB1>(x);
    x = dpp_add<0x4E>(x);
    x = dpp_add<0x141>(x);
    return x;
}

// async global->LDS, 16B/lane; lds dest = wave-uniform base + lane*16
__device__ __forceinline__ void glds16(const bf16* g, void* l) {
    __builtin_amdgcn_global_load_lds((const __attribute__((address_space(1))) void*)g,
                                     (__attribute__((address_space(3))) void*)l, 16, 0, 0);
}

// ---------------- cast fp32 -> bf16 ----------------
__global__ __launch_bounds__(256) void cast_f32_bf16(const float* __restrict__ src,
                                                     bf16* __restrict__ dst, int n4) {
    int i = blockIdx.x * 256 + threadIdx.x;
    if (i < n4) {
        float4 v = ((const float4*)src)[i];
        bf16x4 o = { f2bf(v.x), f2bf(v.y), f2bf(v.z), f2bf(v.w) };
        ((bf16x4*)dst)[i] = o;
    }
}

// ---------------- transpose + cast: fp32 [R][C] -> bf16 [C][R] ----------------
__global__ __launch_bounds__(256) void transpose_cast(const float* __restrict__ src,
                                                      bf16* __restrict__ dst,
                                                      int R, int C) {
    __shared__ float tile[32][33];
    int c0 = blockIdx.x * 32, r0 = blockIdx.y * 32;
    int tx = threadIdx.x, ty = threadIdx.y;
#pragma unroll
    for (int i = 0; i < 32; i += 8) {
        int r = r0 + ty + i, c = c0 + tx;
        tile[ty + i][tx] = (r < R && c < C) ? src[(size_t)r * C + c] : 0.0f;
    }
    __syncthreads();
#pragma unroll
    for (int i = 0; i < 32; i += 8) {
        int rr = c0 + ty + i, cc = r0 + tx;
        if (rr < C && cc < R) dst[(size_t)rr * R + cc] = f2bf(tile[tx][ty + i]);
    }
}

// ---------------- GEMM: C[M,N] = A[M,K] @ Bt[N,K]^T, strided A/C/gate ----------------
template <typename OutT>
__global__ __launch_bounds__(256) void gemm_bt(const bf16* __restrict__ A,
                                               const bf16* __restrict__ Bt,
                                               OutT* __restrict__ C,
                                               int M, int N, int K,
                                               const bf16* __restrict__ gate,
                                               int lda, int ldc, int ldg) {
    __shared__ bf16 As[128 * 32];
    __shared__ bf16 Bs[128 * 32];

    const int n0 = blockIdx.x * 128;
    const int m0 = blockIdx.y * 128;
    const int t = threadIdx.x;
    const int wid = t >> 6, lane = t & 63;
    const int wm = (wid & 1) * 64;
    const int wn = (wid >> 1) * 64;

    f32x4 acc[4][4] = {};

    const int srow = lane >> 2;          // 0..15
    const int scol = (lane & 3) * 8;     // bf16 col offset
    char* AsB = (char*)As;
    char* BsB = (char*)Bs;

    for (int k0 = 0; k0 < K; k0 += 32) {
        glds16(&A[(size_t)(m0 + wid * 16 + srow) * lda + k0 + scol],       AsB + wid * 1024);
        glds16(&A[(size_t)(m0 + 64 + wid * 16 + srow) * lda + k0 + scol],  AsB + 4096 + wid * 1024);
        glds16(&Bt[(size_t)(n0 + wid * 16 + srow) * K + k0 + scol],        BsB + wid * 1024);
        glds16(&Bt[(size_t)(n0 + 64 + wid * 16 + srow) * K + k0 + scol],   BsB + 4096 + wid * 1024);
        __syncthreads();

        const int kh = (lane >> 4) * 8;
        const int lm = lane & 15;
        bf16x8 a[4], b[4];
#pragma unroll
        for (int i = 0; i < 4; i++) a[i] = *(const bf16x8*)&As[(wm + i * 16 + lm) * 32 + kh];
#pragma unroll
        for (int j = 0; j < 4; j++) b[j] = *(const bf16x8*)&Bs[(wn + j * 16 + lm) * 32 + kh];
#pragma unroll
        for (int i = 0; i < 4; i++)
#pragma unroll
            for (int j = 0; j < 4; j++)
                acc[i][j] = __builtin_amdgcn_mfma_f32_16x16x32_bf16(a[i], b[j], acc[i][j], 0, 0, 0);
        __syncthreads();
    }

    const int lm = lane & 15, lq = lane >> 4;
#pragma unroll
    for (int i = 0; i < 4; i++) {
#pragma unroll
        for (int j = 0; j < 4; j++) {
#pragma unroll
            for (int rI = 0; rI < 4; rI++) {
                int row = m0 + wm + i * 16 + lq * 4 + rI;
                int col = n0 + wn + j * 16 + lm;
                float val = acc[i][j][rI];
                if (gate) {
                    float g = bf2f(gate[(size_t)row * ldg + col]);
                    val *= sigmoidf_(g);
                }
                C[(size_t)row * ldc + col] = (OutT)val;
            }
        }
    }
}

// ---------------- zero-centered RMSNorm in place, strided rows ----------------
template <int L>
__global__ __launch_bounds__(256) void zc_rms_kernel(bf16* __restrict__ buf,
                                                     const float* __restrict__ scale,
                                                     int ld) {
    constexpr int NPT = L / 256;
    int row = blockIdx.x;
    int t = threadIdx.x;
    bf16* p = buf + (size_t)row * ld;

    float xv[NPT];
    float s = 0.f, s2 = 0.f;
#pragma unroll
    for (int i = 0; i < NPT; i++) {
        float x = bf2f(p[t + (i << 8)]);
        xv[i] = x;
        s += x;
        s2 += x * x;
    }
    __shared__ float red[2][4];
#pragma unroll
    for (int o = 32; o > 0; o >>= 1) {
        s += __shfl_down(s, o, 64);
        s2 += __shfl_down(s2, o, 64);
    }
    if ((t & 63) == 0) { red[0][t >> 6] = s; red[1][t >> 6] = s2; }
    __syncthreads();
    s  = red[0][0] + red[0][1] + red[0][2] + red[0][3];
    s2 = red[1][0] + red[1][1] + red[1][2] + red[1][3];

    float mean = s / (float)L;
    float var = s2 / (float)L - mean * mean;
    float inv = rsqrtf(var + 1e-5f);
#pragma unroll
    for (int i = 0; i < NPT; i++) {
        float y = (xv[i] - mean) * inv * scale[t + (i << 8)];
        p[t + (i << 8)] = f2bf(y);
    }
}

// ---------------- causal depthwise conv (K=4) + SiLU, strided in, compact out ----------------
__global__ __launch_bounds__(256) void conv_silu(const bf16* __restrict__ xn,
                                                 const float* __restrict__ kern,
                                                 const float* __restrict__ bias,
                                                 bf16* __restrict__ out,
                                                 int Cch, int ldin) {
    int btok = blockIdx.x;
    int tt = btok & (Tc - 1);
    for (int c = threadIdx.x; c < Cch; c += 256) {
        float acc = bias[c];
#pragma unroll
        for (int i = 0; i < 4; i++) {
            int ts = tt - 3 + i;
            if (ts >= 0)
                acc += bf2f(xn[(size_t)(btok - 3 + i) * ldin + c]) * kern[i * Cch + c];
        }
        float y = acc * sigmoidf_(acc);
        out[(size_t)btok * Cch + c] = f2bf(y);
    }
}

// ---------------- alpha / beta: sigmoid(x @ W) for W [D,16], bf16 x ----------------
__global__ __launch_bounds__(64) void alphabeta(const bf16* __restrict__ x,
                                                const float* __restrict__ aw,
                                                const float* __restrict__ bw,
                                                float* __restrict__ af,
                                                float* __restrict__ bfv) {
    int tok = blockIdx.x;
    int lane = threadIdx.x;
    const bf16* xr = x + (size_t)tok * Dc;
    float accA[16] = {};
    float accB[16] = {};
    for (int k = lane; k < Dc; k += 64) {
        float xv = bf2f(xr[k]);
        const float* awr = aw + (size_t)k * Hc;
        const float* bwr = bw + (size_t)k * Hc;
#pragma unroll
        for (int h = 0; h < 16; h++) {
            accA[h] += xv * awr[h];
            accB[h] += xv * bwr[h];
        }
    }
#pragma unroll
    for (int h = 0; h < 16; h++) {
        float a = accA[h], b = accB[h];
#pragma unroll
        for (int o = 32; o > 0; o >>= 1) {
            a += __shfl_down(a, o, 64);
            b += __shfl_down(b, o, 64);
        }
        if (lane == 0) {
            af[(size_t)tok * Hc + h] = sigmoidf_(a);
            bfv[(size_t)tok * Hc + h] = sigmoidf_(b);
        }
    }
}

// ---------------- gated delta-rule scan, v6: NO LDS writes in compute loop ----------------
// r4-r7 lesson: an LDS write (o_tile) inside the step loop forces lgkmcnt(0)-class
// drains on every step's k/q reads (~120-cyc serialized LDS latency — the constant
// ~400 cyc/step across scan3/4/5). v6 streams o directly to global (vmcnt, decoupled
// from ds_read pipelining); compute loop is pure ds_read + VALU + global_store_short.
__global__ __launch_bounds__(256) void scan6(const bf16* __restrict__ qf,
                                             const bf16* __restrict__ kf,
                                             const bf16* __restrict__ vc,
                                             const float* __restrict__ af,
                                             const float* __restrict__ bfv,
                                             bf16* __restrict__ o, int ldo) {
    const int vg = blockIdx.x;                 // 0..3
    const int bh = blockIdx.y;                 // 0..63
    const int b = bh >> 4, h = bh & 15;
    const int tid = threadIdx.x;
    const int wave = tid >> 6, lane = tid & 63;
    const int dgrp = lane & 7;
    const int vloc = wave * 8 + (lane >> 3);   // 0..31

    __shared__ bf16  k_lds[2][SW][64];         // 16 KB
    __shared__ bf16  q_lds[2][SW][64];         // 16 KB
    __shared__ bf16  v_lds[2][SW][32];         //  8 KB
    __shared__ float a_lds[2][SW];
    __shared__ float b_lds[2][SW];

    const size_t base_kq = ((size_t)b * Tc) * QKDc + (size_t)h * DKc;
    const size_t base_v  = ((size_t)b * Tc) * VDc + (size_t)h * DVc + (size_t)vg * 32;
    const size_t base_ab = ((size_t)b * Tc) * Hc + h;
    // per-step global output pointer (col = h*DVc + vg*32 + vloc)
    bf16* optr = o + (size_t)(b * Tc) * ldo + (size_t)h * DVc + (size_t)vg * 32 + vloc;

    float S[8];
#pragma unroll
    for (int j = 0; j < 8; j++) S[j] = 0.f;

    bf16x8 kr[2], qr[2], vr;
    float abr = 0.f;

    auto stage_load = [&](int t0) {
#pragma unroll
        for (int i = 0; i < 2; i++) {
            int c = tid + i * 256;
            int row = c >> 3, col8 = (c & 7) * 8;
            kr[i] = *(const bf16x8*)&kf[base_kq + (size_t)(t0 + row) * QKDc + col8];
            qr[i] = *(const bf16x8*)&qf[base_kq + (size_t)(t0 + row) * QKDc + col8];
        }
        {
            int row = tid >> 2, col8 = (tid & 3) * 8;
            vr = *(const bf16x8*)&vc[base_v + (size_t)(t0 + row) * VDc + col8];
        }
        if (tid < SW) abr = af[base_ab + (size_t)(t0 + tid) * Hc];
        else if (tid < 2 * SW) abr = bfv[base_ab + (size_t)(t0 + tid - SW) * Hc];
    };

    auto stage_write = [&](int buf) {
#pragma unroll
        for (int i = 0; i < 2; i++) {
            int c = tid + i * 256;
            int row = c >> 3, col8 = (c & 7) * 8;
            *(bf16x8*)&k_lds[buf][row][col8] = kr[i];
            *(bf16x8*)&q_lds[buf][row][col8] = qr[i];
        }
        {
            int row = tid >> 2, col8 = (tid & 3) * 8;
            *(bf16x8*)&v_lds[buf][row][col8] = vr;
        }
        if (tid < SW) a_lds[buf][tid] = abr;
        else if (tid < 2 * SW) b_lds[buf][tid - SW] = abr;
    };

    stage_load(0);
    stage_write(0);
    __syncthreads();

    const int nwin = Tc / SW;   // 32
    for (int w = 0; w < nwin; w++) {
        const int buf = w & 1;
        if (w + 1 < nwin) stage_load((w + 1) * SW);   // global->reg, overlaps compute

#pragma unroll 4
        for (int t = 0; t < SW; t++) {
            bf16x8 kk = *(const bf16x8*)&k_lds[buf][t][dgrp * 8];
            bf16x8 qq = *(const bf16x8*)&q_lds[buf][t][dgrp * 8];
            float a  = a_lds[buf][t];
            float bb = b_lds[buf][t];
            float vv = bf2f(v_lds[buf][t][vloc]);

            float kfl[8], qfl[8];
#pragma unroll
            for (int j = 0; j < 8; j++) { kfl[j] = bf2f(kk[j]); qfl[j] = bf2f(qq[j]); }

            float pA = kfl[0] * S[0] + kfl[2] * S[2] + kfl[4] * S[4] + kfl[6] * S[6];
            float pB = kfl[1] * S[1] + kfl[3] * S[3] + kfl[5] * S[5] + kfl[7] * S[7];
            float p = reduce8(pA + pB);

            float delta = bb * (vv - a * p);

            float oA = 0.f, oB = 0.f;
#pragma unroll
            for (int j = 0; j < 8; j++) {
                float s = a * S[j] + delta * kfl[j];
                S[j] = s;
                if (j & 1) oB += qfl[j] * s; else oA += qfl[j] * s;
            }
            float oo = reduce8(oA + oB);
            // direct global store: 8 dgrp==0 lanes/wave write 8 contiguous bf16 (16B)
            if (dgrp == 0) optr[(size_t)(w * SW + t) * ldo] = f2bf(oo);
        }
        __syncthreads();                 // all waves done reading buf
        if (w + 1 < nwin) stage_write((w + 1) & 1);
        __syncthreads();                 // buf^1 fully staged before next window
    }
}

// ---------------- host launch ----------------
extern "C" void kernel_launch(void* const* d_in, const int* in_sizes, int n_in,
                              void* d_out, int out_size, void* d_ws, size_t ws_size,
                              hipStream_t stream) {
    const float* x        = (const float*)d_in[0];
    const float* q_w      = (const float*)d_in[1];
    const float* k_w      = (const float*)d_in[2];
    const float* v_w      = (const float*)d_in[3];
    const float* q_scale  = (const float*)d_in[4];
    const float* k_scale  = (const float*)d_in[5];
    const float* v_scale  = (const float*)d_in[6];
    const float* q_conv_k = (const float*)d_in[7];
    const float* q_conv_b = (const float*)d_in[8];
    const float* k_conv_k = (const float*)d_in[9];
    const float* k_conv_b = (const float*)d_in[10];
    const float* v_conv_k = (const float*)d_in[11];
    const float* v_conv_b = (const float*)d_in[12];
    const float* alpha_w  = (const float*)d_in[13];
    const float* beta_w   = (const float*)d_in[14];
    const float* out_w    = (const float*)d_in[15];
    const float* gate_w   = (const float*)d_in[16];

    // ---- workspace (~175 MB) ----
    char* w = (char*)d_ws;
    bf16* xb  = (bf16*)w; w += (size_t)Mc * Dc * 2;          // 16 MB
    bf16* qwT = (bf16*)w; w += (size_t)QKDc * Dc * 2;        //  2 MB  -- qwT|kwT|vwT|gwT
    bf16* kwT = (bf16*)w; w += (size_t)QKDc * Dc * 2;        //  2 MB     contiguous =
    bf16* vwT = (bf16*)w; w += (size_t)VDc * Dc * 2;         //  4 MB     [5120][1024]
    bf16* gwT = (bf16*)w; w += (size_t)Dc * Dc * 2;          //  2 MB
    bf16* owT = (bf16*)w; w += (size_t)Dc * VDc * 2;         //  4 MB
    bf16* lin_all = (bf16*)w; w += (size_t)Mc * NPRJ * 2;    // 80 MB  [M][5120] q|k|v|g
    bf16* qf = (bf16*)w; w += (size_t)Mc * QKDc * 2;         // 16 MB
    bf16* kf = (bf16*)w; w += (size_t)Mc * QKDc * 2;         // 16 MB
    bf16* vc = (bf16*)w; w += (size_t)Mc * VDc * 2;          // 32 MB
    float* af = (float*)w; w += (size_t)Mc * Hc * 4;
    float* bfv = (float*)w; w += (size_t)Mc * Hc * 4;
    // scan output goes into lin_all cols 0:2048 (q|k sections, dead after convs)
    bf16* o_core = lin_all;

    dim3 tb(32, 8);
    cast_f32_bf16<<<(Mc * Dc / 4 + 255) / 256, 256, 0, stream>>>(x, xb, Mc * Dc / 4);
    transpose_cast<<<dim3(QKDc / 32, Dc / 32), tb, 0, stream>>>(q_w, qwT, Dc, QKDc);
    transpose_cast<<<dim3(QKDc / 32, Dc / 32), tb, 0, stream>>>(k_w, kwT, Dc, QKDc);
    transpose_cast<<<dim3(VDc / 32, Dc / 32), tb, 0, stream>>>(v_w, vwT, Dc, VDc);
    transpose_cast<<<dim3(Dc / 32, Dc / 32), tb, 0, stream>>>(gate_w, gwT, Dc, Dc);
    transpose_cast<<<dim3(Dc / 32, VDc / 32), tb, 0, stream>>>(out_w, owT, VDc, Dc);

    // fused q|k|v|gate projection: one 8192x5120x1024 GEMM (xb fetched once)
    gemm_bt<bf16><<<dim3(NPRJ / 128, Mc / 128), 256, 0, stream>>>(
        xb, qwT, lin_all, Mc, NPRJ, Dc, nullptr, Dc, NPRJ, 0);

    // norms (strided rows inside lin_all)
    zc_rms_kernel<QKDc><<<Mc, 256, 0, stream>>>(lin_all,        q_scale, NPRJ);
    zc_rms_kernel<QKDc><<<Mc, 256, 0, stream>>>(lin_all + 1024, k_scale, NPRJ);
    zc_rms_kernel<VDc><<<Mc, 256, 0, stream>>>(lin_all + 2048,  v_scale, NPRJ);

    // convs: strided in, compact bf16 out
    conv_silu<<<Mc, 256, 0, stream>>>(lin_all,        q_conv_k, q_conv_b, qf, QKDc, NPRJ);
    conv_silu<<<Mc, 256, 0, stream>>>(lin_all + 1024, k_conv_k, k_conv_b, kf, QKDc, NPRJ);
    conv_silu<<<Mc, 256, 0, stream>>>(lin_all + 2048, v_conv_k, v_conv_b, vc, VDc, NPRJ);

    alphabeta<<<Mc, 64, 0, stream>>>(xb, alpha_w, beta_w, af, bfv);

    // no-LDS-write-in-loop delta-rule scan; output strided into lin_all cols 0:2048
    scan6<<<dim3(4, Bc * Hc), 256, 0, stream>>>(qf, kf, vc, af, bfv, o_core, NPRJ);

    // out-projection (A = o_core strided in lin_all) + fused sigmoid gate (cols 4096:5120)
    gemm_bt<float><<<dim3(Dc / 128, Mc / 128), 256, 0, stream>>>(
        o_core, owT, (float*)d_out, Mc, Dc, VDc, lin_all + 4096, NPRJ, Dc, NPRJ);
}